// Round 2
// baseline (176.732 us; speedup 1.0000x reference)
//
#include <hip/hip_runtime.h>
#include <math.h>

// GreyBoxTargetedDropout: rows=65536, cols=1024, P=0.1, PERCENT_DROP=0.5.
// Budget (nodes_to_zero) is exhausted by eligible rows -> random branch dead.
// Kernel 1: per-row k_i via eligibility prefix-sum (single block, ballot scan).
// Kernel 2: one WAVE per row; 8-bit x 4-pass radix select of k-th smallest,
//           zero k smallest (stable ties), scale rest by 1/(1-P).

#define COLS 1024

static __device__ __forceinline__ unsigned int fkey(float f) {
  unsigned int u = __float_as_uint(f);
  return (u & 0x80000000u) ? ~u : (u | 0x80000000u);
}

static __device__ __forceinline__ int wave_incl_scan(int x) {
#pragma unroll
  for (int d = 1; d < 64; d <<= 1) {
    int y = __shfl_up(x, d, 64);
    if ((int)(threadIdx.x & 63) >= d) x += y;
  }
  return x;
}

// ---- kernel 1: karr[row] = k_i (single block, 1024 threads) ---------------
__global__ __launch_bounds__(1024) void k_karr(
    const int* __restrict__ labels, const int* __restrict__ tc, int ntc,
    int rows, long long ntz, int kpr, int* __restrict__ karr) {
  const int t = threadIdx.x;
  const int lane = t & 63, wid = t >> 6;
  const int NT = (rows + 1023) >> 10;  // tiles of 1024 rows; NT <= 64

  __shared__ int wcnt[64 * 16];
  __shared__ int goff[64 * 16];
  __shared__ int wsum[16];

  int tcl[8];
#pragma unroll
  for (int j = 0; j < 8; ++j) tcl[j] = (j < ntc) ? tc[j] : 0x7FFFFFFF;

  unsigned long long bits = 0;
  for (int r = 0; r < NT; ++r) {
    int row = (r << 10) + t;
    int e = 0;
    if (row < rows) {
      int lab = labels[row];
      for (int j = 0; j < ntc && j < 8; ++j) e |= (lab == tcl[j]) ? 1 : 0;
    }
    bits |= ((unsigned long long)e) << r;
    unsigned long long m = __ballot(e);
    if (lane == 0) wcnt[r * 16 + wid] = __popcll(m);
  }
  __syncthreads();

  // exclusive scan of NT*16 group counts (flattened index = global row order)
  int v = (t < NT * 16) ? wcnt[t] : 0;
  int incl = wave_incl_scan(v);
  if (lane == 63) wsum[wid] = incl;
  __syncthreads();
  if (t < 16) {
    int x = wsum[t];
#pragma unroll
    for (int d = 1; d < 16; d <<= 1) {
      int y = __shfl_up(x, d, 16);
      if (t >= d) x += y;
    }
    wsum[t] = x;
  }
  __syncthreads();
  int base = wid ? wsum[wid - 1] : 0;
  if (t < NT * 16) goff[t] = base + incl - v;  // exclusive group offset
  __syncthreads();

  for (int r = 0; r < NT; ++r) {
    int row = (r << 10) + t;
    int e = (row < rows) ? (int)((bits >> r) & 1ull) : 0;
    unsigned long long m = __ballot(e);
    int lanepre = __popcll(m & ((1ull << lane) - 1ull));
    long long eb = (long long)goff[r * 16 + wid] + lanepre;
    long long zb = eb * (long long)kpr;
    if (zb > ntz) zb = ntz;
    long long rem = ntz - zb;
    int ki = 0;
    if (e) {
      if (rem < 0) rem = 0;
      ki = (rem > (long long)kpr) ? kpr : (int)rem;
    }
    if (row < rows) karr[row] = ki;
  }
}

// ---- kernel 2: one wave per row -------------------------------------------
__global__ __launch_bounds__(256) void k_apply(
    const float* __restrict__ in, float* __restrict__ out,
    const int* __restrict__ karr, float scale, int rows) {
  const int t = threadIdx.x;
  const int lane = t & 63, w = t >> 6;
  const int row = blockIdx.x * 4 + w;
  if (row >= rows) return;

  __shared__ unsigned int skeys[4][1024];
  __shared__ int hist[4][256];

  const float4* in4 = (const float4*)(in + (size_t)row * COLS);
  float4* out4 = (float4*)(out + (size_t)row * COLS);

  float4 v[4];
#pragma unroll
  for (int j = 0; j < 4; ++j) v[j] = in4[lane + 64 * j];

  const int k = karr[row];

  if (k == 0) {  // wave-uniform: pure scale-copy
#pragma unroll
    for (int j = 0; j < 4; ++j) {
      float4 o = v[j];
      o.x *= scale; o.y *= scale; o.z *= scale; o.w *= scale;
      out4[lane + 64 * j] = o;
    }
    return;
  }

  unsigned int key[16];
#pragma unroll
  for (int j = 0; j < 4; ++j) {
    key[4 * j + 0] = fkey(v[j].x);
    key[4 * j + 1] = fkey(v[j].y);
    key[4 * j + 2] = fkey(v[j].z);
    key[4 * j + 3] = fkey(v[j].w);
  }

  int* h = hist[w];
  unsigned int prefix = 0;
  int krem = k;
  int tie_cnt = 1;

#pragma unroll
  for (int pass = 0; pass < 4; ++pass) {
    const int shift = 24 - 8 * pass;
    const unsigned int pmask =
        (pass == 0) ? 0u : (0xFFFFFFFFu << (shift + 8));
#pragma unroll
    for (int i = 0; i < 4; ++i) h[lane + 64 * i] = 0;
    __builtin_amdgcn_wave_barrier();
#pragma unroll
    for (int j = 0; j < 16; ++j) {
      if ((key[j] & pmask) == prefix)
        atomicAdd(&h[(key[j] >> shift) & 0xFF], 1);
    }
    __builtin_amdgcn_wave_barrier();
    int b0 = h[4 * lane + 0], b1 = h[4 * lane + 1];
    int b2 = h[4 * lane + 2], b3 = h[4 * lane + 3];
    int c0 = b0, c1 = c0 + b1, c2 = c1 + b2, c3 = c2 + b3;
    int incl = wave_incl_scan(c3);
    int excl = incl - c3;
    unsigned long long m = __ballot(excl < krem && krem <= incl);
    int src = __ffsll(m) - 1;
    int excl_sel = __shfl(excl, src, 64);
    int cc0 = __shfl(c0, src, 64), cc1 = __shfl(c1, src, 64);
    int cc2 = __shfl(c2, src, 64), cc3 = __shfl(c3, src, 64);
    int sub = (krem > excl_sel + cc0 ? 1 : 0) +
              (krem > excl_sel + cc1 ? 1 : 0) +
              (krem > excl_sel + cc2 ? 1 : 0);
    int pm1 = (sub == 0) ? 0 : ((sub == 1) ? cc0 : ((sub == 2) ? cc1 : cc2));
    int cm  = (sub == 0) ? cc0 : ((sub == 1) ? cc1 : ((sub == 2) ? cc2 : cc3));
    prefix |= ((unsigned int)(4 * src + sub)) << shift;
    krem -= excl_sel + pm1;
    tie_cnt = cm - pm1;
  }

  const unsigned int kth = prefix;  // exact key of k-th smallest
  const bool need_stable = (krem != tie_cnt);  // wave-uniform
  if (need_stable) {
    unsigned int* sk = skeys[w];
#pragma unroll
    for (int j = 0; j < 4; ++j)
      ((uint4*)sk)[lane + 64 * j] =
          make_uint4(key[4 * j], key[4 * j + 1], key[4 * j + 2], key[4 * j + 3]);
    __builtin_amdgcn_wave_barrier();
  }

#pragma unroll
  for (int j = 0; j < 4; ++j) {
    float vv[4] = {v[j].x, v[j].y, v[j].z, v[j].w};
    float o[4];
#pragma unroll
    for (int c = 0; c < 4; ++c) {
      unsigned int kk = key[4 * j + c];
      bool z;
      if (kk < kth) z = true;
      else if (kk > kth) z = false;
      else if (!need_stable) z = true;  // zero all ties
      else {
        int idx = 4 * (lane + 64 * j) + c;
        int cnt = 0;
        const unsigned int* sk = skeys[w];
        for (int i = 0; i < idx; ++i) cnt += (sk[i] == kth) ? 1 : 0;
        z = cnt < krem;
      }
      o[c] = z ? 0.0f : vv[c] * scale;
    }
    out4[lane + 64 * j] = make_float4(o[0], o[1], o[2], o[3]);
  }
}

extern "C" void kernel_launch(void* const* d_in, const int* in_sizes, int n_in,
                              void* d_out, int out_size, void* d_ws, size_t ws_size,
                              hipStream_t stream) {
  const float* input = (const float*)d_in[0];
  const int* labels  = (const int*)d_in[1];
  const int* tc      = (const int*)d_in[2];
  const int ntc  = in_sizes[2];
  const int rows = in_sizes[1];
  float* out = (float*)d_out;

  int* karr = (int*)d_ws;

  const long long nodes_to_zero =
      (long long)floor((double)rows * (double)COLS * 0.1);
  const int k_per_row = (int)floor((double)COLS * 0.5);
  const float scale = (float)(1.0 / (1.0 - 0.1));

  hipLaunchKernelGGL(k_karr, dim3(1), dim3(1024), 0, stream,
                     labels, tc, ntc, rows, nodes_to_zero, k_per_row, karr);
  hipLaunchKernelGGL(k_apply, dim3((rows + 3) / 4), dim3(256), 0, stream,
                     input, out, karr, scale, rows);
}